// Round 16
// baseline (70.951 us; speedup 1.0000x reference)
//
#include <hip/hip_runtime.h>
#include <hip/hip_bf16.h>
#include <stdint.h>

// Problem constants (fixed by setup_inputs)
#define KC   256      // concepts
#define DD   256      // feature dim
#define NPROT 1024    // KC*M
#define NQ   32768    // B*KC

// ws layout (bytes); ws_size = 256 MB. First 4096 B zeroed by hipMemsetAsync each launch.
#define OFF_TOT   0                       // float
#define OFF_GTICK 8                       // int
#define OFF_NSEL  16                      // int
#define OFF_TTICK 256                     // int[512] per-tile tickets (2 KB, inside the 4 KB memset)
#define OFF_SEL   4096                    // int[32768] (128 KB)
#define OFF_PN    135168                  // bf16 protos k-major, PRE-SCALED by 10*log2(e) (512 KB)
#define OFF_QN    659456                  // bf16 selected queries k-major: [16 slabs][32768 slots][32B] (16 MB)
#define QSLAB     1048576                 // 32768 * 32 B per k-slab
#define OFF_ACC   17436672                // float2[4 planes][32768 slots] = 1 MB (one plane per chunk)

#define LN2F    0.69314718055994531f
#define C10L2E  14.426950408889634f       // 10 * log2(e): folded into proto scale

typedef __bf16 bf16x8 __attribute__((ext_vector_type(8)));
typedef float  f32x16 __attribute__((ext_vector_type(16)));

static __device__ __forceinline__ unsigned short f2bf(float x) {
  __hip_bfloat16 h = __float2bfloat16(x);
  return __builtin_bit_cast(unsigned short, h);
}

// ---------------- Kernel 1 (merged, r14/r15-proven): protos -> PN | compact+normalize -> QN ----------------
__global__ __launch_bounds__(512) void prep_k(const int* __restrict__ gt,
                                              const float* __restrict__ lv,
                                              const float* __restrict__ protos,
                                              unsigned char* __restrict__ ws) {
  const int blk = blockIdx.x;
  const int tid = threadIdx.x;

  if (blk < 128) {
    // ---- prototypes: one row per wave, 8 waves -> rows blk*8 .. blk*8+7 ----
    const int wv = tid >> 6, lane = tid & 63;
    const int r = blk * 8 + wv;                      // 1024 rows
    const float4 v = ((const float4*)protos)[r * 64 + lane];
    float ss = v.x*v.x + v.y*v.y + v.z*v.z + v.w*v.w;
#pragma unroll
    for (int m = 1; m < 64; m <<= 1) ss += __shfl_xor(ss, m, 64);
    const float sc = C10L2E / fmaxf(sqrtf(ss), 1e-12f);   // fold 10*log2(e)
    uint2 p;
    p.x = (unsigned)f2bf(v.x * sc) | ((unsigned)f2bf(v.y * sc) << 16);
    p.y = (unsigned)f2bf(v.z * sc) | ((unsigned)f2bf(v.w * sc) << 16);
    *(uint2*)(ws + OFF_PN + (lane >> 2) * 32768 + r * 32 + (lane & 3) * 8) = p;
    return;
  }

  // ---- compact (1 atomic/block) + gather+normalize -> QN ----
  __shared__ int wcnt[8], wpre[8];
  __shared__ int sbase, btot;
  __shared__ int list[512];

  const int wv   = tid >> 6, lane = tid & 63;
  const int idx  = (blk - 128) * 512 + tid;          // 64 blocks -> 32768

  const int selme = (gt[idx] == 1);
  const unsigned long long bal = __ballot(selme);
  if (lane == 0) wcnt[wv] = __popcll(bal);
  __syncthreads();
  if (tid == 0) {
    int tot = 0;
#pragma unroll
    for (int u = 0; u < 8; ++u) { wpre[u] = tot; tot += wcnt[u]; }
    btot  = tot;
    sbase = atomicAdd((int*)(ws + OFF_NSEL), tot);
  }
  __syncthreads();

  const int rank = __popcll(bal & ((1ull << lane) - 1ull));
  if (selme) {
    const int loc = wpre[wv] + rank;
    list[loc] = idx;
    ((int*)(ws + OFF_SEL))[sbase + loc] = idx;
  }
  __syncthreads();

  const int grp = tid >> 4, sub = tid & 15;
  const int nr  = btot, sb = sbase;
  for (int r = grp; r < nr; r += 32) {
    const int qi   = list[r];
    const int slot = sb + r;
    float4 vv[4];
#pragma unroll
    for (int u = 0; u < 4; ++u) vv[u] = ((const float4*)lv)[qi * 64 + u * 16 + sub];
    float ss = 0.0f;
#pragma unroll
    for (int u = 0; u < 4; ++u)
      ss += vv[u].x*vv[u].x + vv[u].y*vv[u].y + vv[u].z*vv[u].z + vv[u].w*vv[u].w;
#pragma unroll
    for (int m = 1; m < 16; m <<= 1) ss += __shfl_xor(ss, m, 64);
    const float sc = 1.0f / fmaxf(sqrtf(ss), 1e-12f);
#pragma unroll
    for (int u = 0; u < 4; ++u) {
      uint2 p;
      p.x = (unsigned)f2bf(vv[u].x * sc) | ((unsigned)f2bf(vv[u].y * sc) << 16);
      p.y = (unsigned)f2bf(vv[u].z * sc) | ((unsigned)f2bf(vv[u].w * sc) << 16);
      *(uint2*)(ws + OFF_QN + (u * 4 + (sub >> 2)) * QSLAB + slot * 32 + (sub & 3) * 8) = p;
    }
  }
}

// ---------------- Kernel 2: copy-stage + GEMM + epilogue + FUSED per-tile finish ----------------
// grid: 2048 blocks. tile = bid & 511, c = bid >> 9 (uniform XCD spread of working blocks).
// K-loop/staging byte-identical to r13/r15. New tail: block-level plane reduction in LDS,
// one float2 store per (slot, chunk), per-tile ticket; 4th chunk-block computes the tile's
// contribs and the last tile writes out (finish_k dispatch eliminated).
__global__ __launch_bounds__(256) void main_k(unsigned char* __restrict__ ws,
                                              float* __restrict__ out) {
  __shared__ __align__(16) unsigned char Aq[64 * 512];  // staging; reused as reduction buffer
  __shared__ int lastf;

  const int tid  = threadIdx.x;
  const int w    = tid >> 6;        // wave 0..3
  const int lane = tid & 63;
  const int hi   = lane >> 5;
  const int l31  = lane & 31;

  const int tile = (int)(blockIdx.x & 511);  // 0..511 (64 slots each)
  const int c    = (int)(blockIdx.x >> 9);   // proto chunk of 256 rows

  const int n_sel = *(const int*)(ws + OFF_NSEL);
  const int base  = tile * 64;
  if (base >= n_sel) {
    if (blockIdx.x == 0 && tid == 0) out[0] = 0.0f;  // n_sel==0 defensive path
    return;
  }
  const int* sel = (const int*)(ws + OFF_SEL);

  // per-lane concept ids for the epilogue
  int kqr[2];
#pragma unroll
  for (int j = 0; j < 2; ++j) {
    const int slot = base + j * 32 + l31;
    const int q = (slot < n_sel) ? sel[slot] : sel[base];
    kqr[j] = q & (KC - 1);
  }

  // A-fragment bases: chain a0 = proto rows c*256 + w*64 + l31, a1 = +32 rows
  const unsigned char* pn0 = ws + OFF_PN + (c * 256 + w * 64 + l31) * 32 + hi * 16;
  const unsigned char* pn1 = pn0 + 32 * 32;

  // depth-4 prefetch per chain (8 loads in flight), issued BEFORE the copy stage
  bf16x8 pa0[4], pa1[4];
#pragma unroll
  for (int p = 0; p < 4; ++p) {
    pa0[p] = *(const bf16x8*)(pn0 + p * 32768);
    pa1[p] = *(const bf16x8*)(pn1 + p * 32768);
  }

  // ---- stage 64 normalized query rows from QN -> swizzled LDS: pure copy ----
  const unsigned char* qn = ws + OFF_QN;
  const int last = n_sel - 1;
#pragma unroll
  for (int i = 0; i < 4; ++i) {
    const int unit = i * 256 + tid;          // 1024 units: (slab s, row r)
    const int s = unit >> 6, r = unit & 63;
    const int slot = min(base + r, last);    // clamp tail-tile padding
    const unsigned char* src = qn + s * QSLAB + slot * 32;
    const uint4 d0 = *(const uint4*)(src);
    const uint4 d1 = *(const uint4*)(src + 16);
    const int swz = ((r & 7) << 4) ^ (((r >> 3) & 3) << 7);
    *(uint4*)(Aq + r * 512 + ((s * 32) ^ swz))      = d0;
    *(uint4*)(Aq + r * 512 + ((s * 32 + 16) ^ swz)) = d1;
  }
  __syncthreads();

  f32x16 acc[2][2];
#pragma unroll
  for (int i = 0; i < 2; ++i)
#pragma unroll
    for (int j = 0; j < 2; ++j)
#pragma unroll
      for (int t = 0; t < 16; ++t) acc[i][j][t] = 0.0f;

  const int bswz = ((l31 & 7) << 4) ^ (((l31 >> 3) & 3) << 7);

  // ---- K loop: 16 steps, 4 independent MFMA chains, depth-4 ring per A-chain ----
#pragma unroll
  for (int k = 0; k < 16; ++k) {
    const bf16x8 a0 = pa0[k & 3];
    const bf16x8 a1 = pa1[k & 3];
    pa0[k & 3] = *(const bf16x8*)(pn0 + ((k + 4) & 15) * 32768);
    pa1[k & 3] = *(const bf16x8*)(pn1 + ((k + 4) & 15) * 32768);
    const int bc = (k * 32 + hi * 16) ^ bswz;
    const bf16x8 b0 = *(const bf16x8*)(Aq + l31 * 512 + bc);
    const bf16x8 b1 = *(const bf16x8*)(Aq + (32 + l31) * 512 + bc);
    acc[0][0] = __builtin_amdgcn_mfma_f32_32x32x16_bf16(a0, b0, acc[0][0], 0, 0, 0);
    acc[0][1] = __builtin_amdgcn_mfma_f32_32x32x16_bf16(a0, b1, acc[0][1], 0, 0, 0);
    acc[1][0] = __builtin_amdgcn_mfma_f32_32x32x16_bf16(a1, b0, acc[1][0], 0, 0, 0);
    acc[1][1] = __builtin_amdgcn_mfma_f32_32x32x16_bf16(a1, b1, acc[1][1], 0, 0, 0);
  }

  // ---- epilogue: acc element IS y (protos pre-scaled); L += 2^y; P += y on positives ----
  float l_acc[2] = {0.f, 0.f}, p_acc[2] = {0.f, 0.f};
#pragma unroll
  for (int i = 0; i < 2; ++i) {
    const int r4base = c * 64 + w * 16 + i * 8 + hi;   // proto row>>2 = r4base + 2*g
#pragma unroll
    for (int j = 0; j < 2; ++j) {
      float l4[4] = {0.f, 0.f, 0.f, 0.f};
      float p4[4] = {0.f, 0.f, 0.f, 0.f};
#pragma unroll
      for (int g = 0; g < 4; ++g) {
        const float pm = (r4base + 2 * g == kqr[j]) ? 1.0f : 0.0f;
#pragma unroll
        for (int t = 0; t < 4; ++t) {
          const float y = acc[i][j][g * 4 + t];
          l4[t] += __builtin_amdgcn_exp2f(y);
          p4[t] = fmaf(pm, y, p4[t]);
        }
      }
      l_acc[j] += (l4[0] + l4[1]) + (l4[2] + l4[3]);
      p_acc[j] += (p4[0] + p4[1]) + (p4[2] + p4[3]);
    }
  }

  // combine the two row-half lanes (lane ^ 32)
#pragma unroll
  for (int j = 0; j < 2; ++j) {
    l_acc[j] += __shfl_xor(l_acc[j], 32, 64);
    p_acc[j] += __shfl_xor(p_acc[j], 32, 64);
  }

  // ---- block-level plane reduction in LDS (reuse Aq), one float2 store per slot ----
  __syncthreads();                       // all waves done reading Aq
  float* red = (float*)Aq;               // [4 waves][64 slots][2]
  if (hi == 0) {
#pragma unroll
    for (int j = 0; j < 2; ++j) {
      const int s = j * 32 + l31;
      red[(w * 64 + s) * 2]     = l_acc[j];
      red[(w * 64 + s) * 2 + 1] = p_acc[j];
    }
  }
  __syncthreads();
  if (tid < 64) {
    float L = 0.f, P = 0.f;
#pragma unroll
    for (int u = 0; u < 4; ++u) {
      L += red[(u * 64 + tid) * 2];
      P += red[(u * 64 + tid) * 2 + 1];
    }
    float2 v2; v2.x = L; v2.y = P;
    ((float2*)(ws + OFF_ACC))[c * 32768 + base + tid] = v2;   // plane c, collision-free
    __threadfence();                     // push this thread's store to coherence point
  }
  __syncthreads();

  // ---- per-tile ticket; 4th chunk-block finishes the tile ----
  if (tid == 0) {
    __threadfence();
    lastf = (atomicAdd((int*)(ws + OFF_TTICK) + tile, 1) == 3);
  }
  __syncthreads();
  if (!lastf) return;

  float contrib = 0.0f;
  if (tid < 64) {
    const int slot = base + tid;
    if (slot < n_sel) {
      float L = 0.f, P = 0.f;
#pragma unroll
      for (int u = 0; u < 4; ++u) {
        float* p2 = (float*)(ws + OFF_ACC) + (u * 32768 + slot) * 2;
        L += atomicAdd(p2, 0.0f);        // coherent reads (cross-XCD safe)
        P += atomicAdd(p2 + 1, 0.0f);
      }
      contrib = LN2F * (4.0f * __builtin_amdgcn_logf(L) - P);  // v_log_f32 = log2
    }
#pragma unroll
    for (int m = 1; m < 64; m <<= 1) contrib += __shfl_xor(contrib, m, 64);
    if (tid == 0) {
      atomicAdd((float*)(ws + OFF_TOT), contrib);
      __threadfence();
      const int g = atomicAdd((int*)(ws + OFF_GTICK), 1);
      const int n_tiles = (n_sel + 63) >> 6;
      if (g == n_tiles - 1)              // last tile: all TOT adds fenced before tickets
        out[0] = atomicAdd((float*)(ws + OFF_TOT), 0.0f) / (4.0f * (float)n_sel);
    }
  }
}

extern "C" void kernel_launch(void* const* d_in, const int* in_sizes, int n_in,
                              void* d_out, int out_size, void* d_ws, size_t ws_size,
                              hipStream_t stream) {
  const float* lv     = (const float*)d_in[0];   // (128,256,256) f32
  const float* protos = (const float*)d_in[1];   // (1024,256,1,1) f32
  const int*   gt     = (const int*)d_in[2];     // (128,256) i32
  (void)in_sizes; (void)n_in; (void)out_size; (void)ws_size;
  unsigned char* ws = (unsigned char*)d_ws;

  hipMemsetAsync(d_ws, 0, 4096, stream);         // zero TOT/GTICK/NSEL + 512 tile tickets
  prep_k<<<192, 512, 0, stream>>>(gt, lv, protos, ws);
  main_k<<<2048, 256, 0, stream>>>(ws, (float*)d_out);
}

// Round 17
// 35.527 us; speedup vs baseline: 1.9971x; 1.9971x over previous
//
#include <hip/hip_runtime.h>
#include <hip/hip_bf16.h>
#include <stdint.h>

// Problem constants (fixed by setup_inputs)
#define KC   256      // concepts
#define DD   256      // feature dim
#define NPROT 1024    // KC*M
#define NQ   32768    // B*KC

// ws layout (bytes); ws_size = 256 MB. Total used ~21.6 MB.
#define OFF_NSEL 0                        // int   (zeroed by hipMemsetAsync)
#define OFF_TOT  8                        // float (zeroed by hipMemsetAsync)
#define OFF_TICK 16                       // int   (zeroed by hipMemsetAsync)
#define OFF_SEL  256                      // int[32768] (128 KB)
#define OFF_PN   131328                   // bf16 protos k-major, PRE-SCALED by 10*log2(e) (512 KB)
#define OFF_QN   655616                   // bf16 selected queries k-major: [16 slabs][32768 slots][32B] (16 MB)
#define QSLAB    1048576                  // 32768 * 32 B per k-slab
#define OFF_ACC  17432832                 // float2[16 planes][32768 slots] = 4 MB, collision-free
#define ACC_STRIDE 32768                  // float2 per (c,w) plane

#define LN2F    0.69314718055994531f
#define C10L2E  14.426950408889634f       // 10 * log2(e): folded into proto scale

typedef __bf16 bf16x8 __attribute__((ext_vector_type(8)));
typedef float  f32x16 __attribute__((ext_vector_type(16)));

static __device__ __forceinline__ unsigned short f2bf(float x) {
  __hip_bfloat16 h = __float2bfloat16(x);
  return __builtin_bit_cast(unsigned short, h);
}

// ---------------- Kernel 1: protos -> PN (blocks 0..127) | compact only (128..191) ----------------
// r15's prep_k with the gather+normalize loop REMOVED (re-sharded into qnorm_k below):
// the 16 MB gather was welded to 64 blocks = 1/4 of the chip.
__global__ __launch_bounds__(512) void prep_k(const int* __restrict__ gt,
                                              const float* __restrict__ protos,
                                              unsigned char* __restrict__ ws) {
  const int blk = blockIdx.x;
  const int tid = threadIdx.x;

  if (blk < 128) {
    // ---- prototypes: one row per wave, 8 waves -> rows blk*8 .. blk*8+7 ----
    const int wv = tid >> 6, lane = tid & 63;
    const int r = blk * 8 + wv;                      // 1024 rows
    const float4 v = ((const float4*)protos)[r * 64 + lane];
    float ss = v.x*v.x + v.y*v.y + v.z*v.z + v.w*v.w;
#pragma unroll
    for (int m = 1; m < 64; m <<= 1) ss += __shfl_xor(ss, m, 64);
    const float sc = C10L2E / fmaxf(sqrtf(ss), 1e-12f);   // fold 10*log2(e)
    uint2 p;
    p.x = (unsigned)f2bf(v.x * sc) | ((unsigned)f2bf(v.y * sc) << 16);
    p.y = (unsigned)f2bf(v.z * sc) | ((unsigned)f2bf(v.w * sc) << 16);
    *(uint2*)(ws + OFF_PN + (lane >> 2) * 32768 + r * 32 + (lane & 3) * 8) = p;
    return;
  }

  // ---- compact (1 atomic/block): ballot -> block prefix -> SEL ----
  __shared__ int wcnt[8], wpre[8];
  __shared__ int sbase;

  const int wv   = tid >> 6, lane = tid & 63;
  const int idx  = (blk - 128) * 512 + tid;          // 64 blocks -> 32768

  const int selme = (gt[idx] == 1);
  const unsigned long long bal = __ballot(selme);
  if (lane == 0) wcnt[wv] = __popcll(bal);
  __syncthreads();
  if (tid == 0) {
    int tot = 0;
#pragma unroll
    for (int u = 0; u < 8; ++u) { wpre[u] = tot; tot += wcnt[u]; }
    sbase = atomicAdd((int*)(ws + OFF_NSEL), tot);
  }
  __syncthreads();

  const int rank = __popcll(bal & ((1ull << lane) - 1ull));
  if (selme)
    ((int*)(ws + OFF_SEL))[sbase + wpre[wv] + rank] = idx;
}

// ---------------- Kernel 2: gather + L2-normalize selected rows -> QN (full-machine shard) ----------------
// 512 blocks x 256 threads; block b owns slots b*64 .. b*64+63 (~256 working blocks).
__global__ __launch_bounds__(256) void qnorm_k(const float* __restrict__ lv,
                                               unsigned char* __restrict__ ws) {
  const int n_sel = *(const int*)(ws + OFF_NSEL);
  const int base  = (int)blockIdx.x * 64;
  if (base >= n_sel) return;
  const int* sel = (const int*)(ws + OFF_SEL);

  const int grp = threadIdx.x >> 4, sub = threadIdx.x & 15;   // 16 groups of 16 lanes
#pragma unroll
  for (int t = 0; t < 4; ++t) {
    const int slot = base + grp * 4 + t;
    if (slot >= n_sel) break;
    const int qi = sel[slot];
    float4 vv[4];
#pragma unroll
    for (int u = 0; u < 4; ++u) vv[u] = ((const float4*)lv)[qi * 64 + u * 16 + sub];
    float ss = 0.0f;
#pragma unroll
    for (int u = 0; u < 4; ++u)
      ss += vv[u].x*vv[u].x + vv[u].y*vv[u].y + vv[u].z*vv[u].z + vv[u].w*vv[u].w;
#pragma unroll
    for (int m = 1; m < 16; m <<= 1) ss += __shfl_xor(ss, m, 64);
    const float sc = 1.0f / fmaxf(sqrtf(ss), 1e-12f);
#pragma unroll
    for (int u = 0; u < 4; ++u) {
      uint2 p;
      p.x = (unsigned)f2bf(vv[u].x * sc) | ((unsigned)f2bf(vv[u].y * sc) << 16);
      p.y = (unsigned)f2bf(vv[u].z * sc) | ((unsigned)f2bf(vv[u].w * sc) << 16);
      // element e = u*64 + sub*4 -> slab = u*4 + (sub>>2), byte = (sub&3)*8
      *(uint2*)(ws + OFF_QN + (u * 4 + (sub >> 2)) * QSLAB + slot * 32 + (sub & 3) * 8) = p;
    }
  }
}

// ---------------- Kernel 3 (r13/r15-proven, byte-identical): copy-stage + GEMM + exp2/pos partials ----------------
// grid: 2048 blocks. tile = bid & 511, c = bid >> 9 (uniform XCD spread of working blocks).
__global__ __launch_bounds__(256) void main_k(unsigned char* __restrict__ ws) {
  __shared__ __align__(16) unsigned char Aq[64 * 512];  // 64 query rows, bf16, swizzled (32 KB)

  const int tid  = threadIdx.x;
  const int w    = tid >> 6;        // wave 0..3
  const int lane = tid & 63;
  const int hi   = lane >> 5;
  const int l31  = lane & 31;

  const int tile = (int)(blockIdx.x & 511);  // 0..511 (64 slots each)
  const int c    = (int)(blockIdx.x >> 9);   // proto chunk of 256 rows

  const int n_sel = *(const int*)(ws + OFF_NSEL);
  const int base  = tile * 64;
  if (base >= n_sel) return;
  const int* sel = (const int*)(ws + OFF_SEL);

  // per-lane slot info for epilogue + store
  int valid[2], kqr[2];
#pragma unroll
  for (int j = 0; j < 2; ++j) {
    const int slot = base + j * 32 + l31;
    valid[j] = slot < n_sel;
    const int q = valid[j] ? sel[slot] : sel[base];
    kqr[j] = q & (KC - 1);
  }

  // A-fragment bases: chain a0 = proto rows c*256 + w*64 + l31, a1 = +32 rows
  const unsigned char* pn0 = ws + OFF_PN + (c * 256 + w * 64 + l31) * 32 + hi * 16;
  const unsigned char* pn1 = pn0 + 32 * 32;

  // depth-4 prefetch per chain (8 loads in flight), issued BEFORE the copy stage
  bf16x8 pa0[4], pa1[4];
#pragma unroll
  for (int p = 0; p < 4; ++p) {
    pa0[p] = *(const bf16x8*)(pn0 + p * 32768);
    pa1[p] = *(const bf16x8*)(pn1 + p * 32768);
  }

  // ---- stage 64 normalized query rows from QN -> swizzled LDS: pure copy, no math ----
  const unsigned char* qn = ws + OFF_QN;
  const int last = n_sel - 1;
#pragma unroll
  for (int i = 0; i < 4; ++i) {
    const int unit = i * 256 + tid;          // 1024 units: (slab s, row r)
    const int s = unit >> 6, r = unit & 63;
    const int slot = min(base + r, last);    // clamp tail-tile padding to a valid slot
    const unsigned char* src = qn + s * QSLAB + slot * 32;
    const uint4 d0 = *(const uint4*)(src);
    const uint4 d1 = *(const uint4*)(src + 16);
    const int swz = ((r & 7) << 4) ^ (((r >> 3) & 3) << 7);
    *(uint4*)(Aq + r * 512 + ((s * 32) ^ swz))      = d0;
    *(uint4*)(Aq + r * 512 + ((s * 32 + 16) ^ swz)) = d1;
  }
  __syncthreads();

  f32x16 acc[2][2];
#pragma unroll
  for (int i = 0; i < 2; ++i)
#pragma unroll
    for (int j = 0; j < 2; ++j)
#pragma unroll
      for (int t = 0; t < 16; ++t) acc[i][j][t] = 0.0f;

  const int bswz = ((l31 & 7) << 4) ^ (((l31 >> 3) & 3) << 7);  // rows l31 / 32+l31 identical

  // ---- K loop: 16 steps, 4 independent MFMA chains, depth-4 ring per A-chain ----
#pragma unroll
  for (int k = 0; k < 16; ++k) {
    const bf16x8 a0 = pa0[k & 3];
    const bf16x8 a1 = pa1[k & 3];
    pa0[k & 3] = *(const bf16x8*)(pn0 + ((k + 4) & 15) * 32768);
    pa1[k & 3] = *(const bf16x8*)(pn1 + ((k + 4) & 15) * 32768);
    const int bc = (k * 32 + hi * 16) ^ bswz;
    const bf16x8 b0 = *(const bf16x8*)(Aq + l31 * 512 + bc);
    const bf16x8 b1 = *(const bf16x8*)(Aq + (32 + l31) * 512 + bc);
    acc[0][0] = __builtin_amdgcn_mfma_f32_32x32x16_bf16(a0, b0, acc[0][0], 0, 0, 0);
    acc[0][1] = __builtin_amdgcn_mfma_f32_32x32x16_bf16(a0, b1, acc[0][1], 0, 0, 0);
    acc[1][0] = __builtin_amdgcn_mfma_f32_32x32x16_bf16(a1, b0, acc[1][0], 0, 0, 0);
    acc[1][1] = __builtin_amdgcn_mfma_f32_32x32x16_bf16(a1, b1, acc[1][1], 0, 0, 0);
  }

  // ---- epilogue: acc element IS y (protos pre-scaled); L += 2^y; P += y on positives ----
  float l_acc[2] = {0.f, 0.f}, p_acc[2] = {0.f, 0.f};
#pragma unroll
  for (int i = 0; i < 2; ++i) {
    const int r4base = c * 64 + w * 16 + i * 8 + hi;   // proto row>>2 = r4base + 2*g
#pragma unroll
    for (int j = 0; j < 2; ++j) {
      float l4[4] = {0.f, 0.f, 0.f, 0.f};
      float p4[4] = {0.f, 0.f, 0.f, 0.f};
#pragma unroll
      for (int g = 0; g < 4; ++g) {
        const float pm = (r4base + 2 * g == kqr[j]) ? 1.0f : 0.0f;
#pragma unroll
        for (int t = 0; t < 4; ++t) {
          const float y = acc[i][j][g * 4 + t];
          l4[t] += __builtin_amdgcn_exp2f(y);
          p4[t] = fmaf(pm, y, p4[t]);
        }
      }
      l_acc[j] += (l4[0] + l4[1]) + (l4[2] + l4[3]);
      p_acc[j] += (p4[0] + p4[1]) + (p4[2] + p4[3]);
    }
  }

  // combine the two row-half lanes (lane ^ 32); one coalesced store per (slot, chunk, wave)
#pragma unroll
  for (int j = 0; j < 2; ++j) {
    l_acc[j] += __shfl_xor(l_acc[j], 32, 64);
    p_acc[j] += __shfl_xor(p_acc[j], 32, 64);
  }
  if (hi == 0) {
    float2* accb = (float2*)(ws + OFF_ACC) + (c * 4 + w) * ACC_STRIDE;
#pragma unroll
    for (int j = 0; j < 2; ++j) {
      if (valid[j]) {
        const int slot = base + j * 32 + l31;
        float2 v2; v2.x = l_acc[j]; v2.y = p_acc[j];
        accb[slot] = v2;
      }
    }
  }
}

// ---------------- Kernel 4 (r15-proven): per-slot contribution + grid sum + final divide ----------------
__global__ __launch_bounds__(256) void finish_k(unsigned char* __restrict__ ws,
                                                float* __restrict__ out) {
  __shared__ float accs[4];
  const int n_sel = *(const int*)(ws + OFF_NSEL);
  const int i = blockIdx.x * 256 + threadIdx.x;   // 128 blocks -> 32768 slots
  float contrib = 0.0f;
  if (i < n_sel) {
    const float2* a = (const float2*)(ws + OFF_ACC);
    float L = 0.0f, P = 0.0f;
#pragma unroll
    for (int u = 0; u < 16; ++u) {           // 16 (c,w) planes, coalesced across threads
      const float2 v = a[u * ACC_STRIDE + i];
      L += v.x; P += v.y;
    }
    contrib = LN2F * (4.0f * __builtin_amdgcn_logf(L) - P);  // v_log_f32 = log2
  }
#pragma unroll
  for (int m = 1; m < 64; m <<= 1) contrib += __shfl_xor(contrib, m, 64);
  if ((threadIdx.x & 63) == 0) accs[threadIdx.x >> 6] = contrib;
  __syncthreads();
  if (threadIdx.x == 0) {
    atomicAdd((float*)(ws + OFF_TOT), (accs[0] + accs[1]) + (accs[2] + accs[3]));
    __threadfence();
    const int t = atomicAdd((int*)(ws + OFF_TICK), 1);
    if (t == 127) {   // last block: all TOT adds fenced before their tickets
      const float total = atomicAdd((float*)(ws + OFF_TOT), 0.0f);  // coherent read
      out[0] = (n_sel > 0) ? total / (4.0f * (float)n_sel) : 0.0f;
    }
  }
}

extern "C" void kernel_launch(void* const* d_in, const int* in_sizes, int n_in,
                              void* d_out, int out_size, void* d_ws, size_t ws_size,
                              hipStream_t stream) {
  const float* lv     = (const float*)d_in[0];   // (128,256,256) f32
  const float* protos = (const float*)d_in[1];   // (1024,256,1,1) f32
  const int*   gt     = (const int*)d_in[2];     // (128,256) i32
  (void)in_sizes; (void)n_in; (void)out_size; (void)ws_size;
  unsigned char* ws = (unsigned char*)d_ws;

  hipMemsetAsync(d_ws, 0, 256, stream);          // zero NSEL/TOT/TICK
  prep_k<<<192, 512, 0, stream>>>(gt, protos, ws);
  qnorm_k<<<512, 256, 0, stream>>>(lv, ws);
  main_k<<<2048, 256, 0, stream>>>(ws);
  finish_k<<<128, 256, 0, stream>>>(ws, (float*)d_out);
}